// Round 5
// baseline (231.927 us; speedup 1.0000x reference)
//
#include <hip/hip_runtime.h>

// SNN conv layer: 3x3x16->64 conv (SAME) on 512x512 NHWC + old_potentials,
// threshold 1.0 -> (spikes, reset potentials).
// R5: bf16 implicit-GEMM via mfma_f32_16x16x32_bf16 (93.5us kernel).
// R6: A=weights/co, B=pixels swap -> dwordx4 epilogue (~78us).
// R7: entry-prefetch + TY=4 + prepacked weights + NT stores: NEUTRAL.
// R8: barrier-pipelined persistent blocks: NEUTRAL (barriers re-lockstep).
// R9: LDS-free streaming: NEUTRAL (~<80us). Common flaw of R6-R9: per-wave
//   prefetch distance ~1 vs oldp HBM latency ~2160cy -> each wave exposes
//   ~2000 stall cycles per 200-cycle tile -> bursty memory issue, 2.8 TB/s,
//   all util counters ~0 (latency-bound).
// R10: register-resident distance-3 pipeline, zero barriers, zero LDS:
//   - weights re-laid-out by setup into FRAGMENT order [ks5][nt][lane] so a
//     wave's weight load is 1KB contiguous (R9 layout was a 64-line scatter);
//     all 20 frags hoisted per block (80 VGPR), issued first so their vmcnt
//     wait never drains the pixel/oldp prefetch stream;
//   - 8 y-tiles per block (grid 512 = exactly 2 blocks/CU, tail-free);
//     prologue issues tiles 0..2; loop: compute(t), epilogue(t), issue(t+3);
//   - fully unrolled/SSA (compile-time indices only); counted vmcnt keeps
//     3 tiles x 9KB per wave in flight -> ~55MB device-wide >> 5.4MB needed
//     to saturate HBM at 900ns -> BW-bound, not latency-bound.

#define H 512
#define W 512
#define CI 16
#define CO 64
#define PW 514               // padded width/height
#define PAD_PX (PW * PW)
#define W3_OFF_U16 0         // weight fragments: 1280 x 16B = 20KB
#define IN_OFF_U16 32768     // padded input at d_ws byte 65536
#define NTILES 8             // y-tiles per block (4 rows each, 1 row/wave)
#define PF 3                 // prefetch distance (3 buffers live)

typedef float v4f __attribute__((ext_vector_type(4)));
typedef float f32x4 __attribute__((ext_vector_type(4)));
typedef short short8 __attribute__((ext_vector_type(8)));
typedef unsigned int uint4v __attribute__((ext_vector_type(4)));

__device__ __forceinline__ unsigned int pack2bf(float f0, float f1) {
    // round-to-nearest-even bf16 truncation of two floats, packed
    unsigned u0 = __builtin_bit_cast(unsigned, f0);
    unsigned u1 = __builtin_bit_cast(unsigned, f1);
    u0 = (u0 + 0x7FFFu + ((u0 >> 16) & 1u)) >> 16;
    u1 = (u1 + 0x7FFFu + ((u1 >> 16) & 1u)) >> 16;
    return u0 | (u1 << 16);
}

// ---- setup: blocks 0..N-2: pad+convert input f32 -> bf16 [514][514][16]
//            last block: build weight FRAGMENTS bf16 [ks5][nt][lane][8]
__global__ void snn_setup(const float* __restrict__ in,
                          const float* __restrict__ w,
                          unsigned short* __restrict__ ws)
{
    const int tid = threadIdx.x;
    if (blockIdx.x == gridDim.x - 1) {
        // fragment f = (ks5*4 + nt)*64 + lane; element j = w[k0+j][co] where
        // co = nt*16 + (lane&15), k0 = ks5<4 ? ks5*32+(lane>>4)*8
        //                                    : 128+((lane>>4)&1)*8.
        // All k0+j <= 143 (real taps) -> no zero tail needed on A side.
        uint4v* wf = (uint4v*)(ws + W3_OFF_U16);
        #pragma unroll
        for (int i = 0; i < 5; ++i) {
            const int f    = i * 256 + tid;        // 0..1279
            const int ks5  = f >> 8;
            const int rem  = f & 255;
            const int nt   = rem >> 6;
            const int lane = rem & 63;
            const int r    = lane & 15;
            const int quad = lane >> 4;
            const int k0   = (ks5 < 4) ? (ks5 * 32 + quad * 8)
                                       : (128 + (quad & 1) * 8);
            const int co   = nt * 16 + r;
            uint4v v;
            #pragma unroll
            for (int m = 0; m < 4; ++m)
                v[m] = pack2bf(w[(k0 + 2 * m) * CO + co],
                               w[(k0 + 2 * m + 1) * CO + co]);
            wf[f] = v;
        }
        return;
    }
    // ---- padded input pixel (row 0 / col 0 / row 513 / col 513 are zero;
    // the zero border doubles as the k-pad source for the tap-8 fragment)
    const int p = blockIdx.x * 256 + tid;
    if (p >= PAD_PX) return;
    const int py = p / PW, px = p - py * PW;
    uint4v pk0 = (uint4v)0u, pk1 = (uint4v)0u;
    if (py >= 1 && py <= H && px >= 1 && px <= W) {
        const v4f* q = (const v4f*)(in + ((py - 1) * W + (px - 1)) * CI);
        v4f a = q[0], b = q[1], c = q[2], d = q[3];
        pk0 = (uint4v){pack2bf(a.x, a.y), pack2bf(a.z, a.w),
                       pack2bf(b.x, b.y), pack2bf(b.z, b.w)};
        pk1 = (uint4v){pack2bf(c.x, c.y), pack2bf(c.z, c.w),
                       pack2bf(d.x, d.y), pack2bf(d.z, d.w)};
    }
    uint4v* dst = (uint4v*)(ws + IN_OFF_U16 + p * CI);
    dst[0] = pk0;
    dst[1] = pk1;
}

__global__ __launch_bounds__(256, 2)
void snn_conv_mfma(const unsigned short* __restrict__ ws,
                   const float* __restrict__ oldp,
                   float* __restrict__ out_spk,
                   float* __restrict__ out_pot)
{
    const unsigned short* pin = ws + IN_OFF_U16;   // [PW][PW][16] bf16, padded

    const int tid  = threadIdx.x;
    const int bx   = blockIdx.x & 31;    // 32 x-tiles (16 px each)
    const int g    = blockIdx.x >> 5;    // 16 y-groups (32 rows each)
    const int lane = tid & 63;
    const int wv   = tid >> 6;           // wave 0..3 -> one row per tile
    const int r    = lane & 15;          // pixel-within-16 (B/D) / co-within-16 (A)
    const int quad = lane >> 4;          // 0..3
    const int half = quad & 1;           // ci-half for pixel fragment
    const int tsel = quad >> 1;          // tap parity within K-step

    const int gx  = bx * 16 + r;         // this lane's output col
    const int gyB = g * (4 * NTILES) + wv;   // row of tile 0

    // ---- hoisted weight fragments: 20 x 16B/lane, each wave-instr reads
    // 1KB contiguous; issued FIRST so their vmcnt wait drains nothing else.
    short8 bf[5][4];
    #pragma unroll
    for (int ks5 = 0; ks5 < 5; ++ks5)
        #pragma unroll
        for (int nt = 0; nt < 4; ++nt)
            bf[ks5][nt] = *(const short8*)&ws[(ks5 * 256 + nt * 64 + lane) * 8];

    // per-tile in-flight state; fully unrolled -> SSA, liveness ~PF buffers
    short8 af[NTILES][5];
    f32x4  oldv[NTILES][4];

    auto issue = [&](int t) {
        const int gy = gyB + t * 4;
        const int eb = (gy * W + gx) * CO + quad * 4;
        #pragma unroll
        for (int nt = 0; nt < 4; ++nt)
            oldv[t][nt] = *(const f32x4*)(oldp + eb + nt * 16);
        #pragma unroll
        for (int ks5 = 0; ks5 < 4; ++ks5) {
            const int t8 = 2 * ks5 + tsel;
            const int dy = t8 / 3, dx = t8 % 3;
            af[t][ks5] = *(const short8*)
                &pin[((gy + dy) * PW + (gx + dx)) * CI + half * 8];
        }
        // tap-8 fragment: quad>=2 covers k=144..159 -> read the all-zero
        // padded row 0 instead of a data-cndmask (address select is 1 op).
        const int p4 = (quad < 2) ? ((gy + 2) * PW + (gx + 2)) : gx;
        af[t][4] = *(const short8*)&pin[p4 * CI + half * 8];
    };

    issue(0);
    issue(1);
    issue(2);

    #pragma unroll
    for (int t = 0; t < NTILES; ++t) {
        // compute: A = weight frag (M=co), B = pixel frag (N=pixel)
        f32x4 acc[4] = {};
        #pragma unroll
        for (int ks5 = 0; ks5 < 5; ++ks5)
            #pragma unroll
            for (int nt = 0; nt < 4; ++nt)
                acc[nt] = __builtin_amdgcn_mfma_f32_16x16x32_bf16(
                    bf[ks5][nt], af[t][ks5], acc[nt], 0, 0, 0);

        // epilogue: D col=lane&15 (pixel), row=quad*4+reg (co-within-16)
        // -> each f32x4 acc reg = 4 contiguous co -> dwordx4 stores.
        const int gy = gyB + t * 4;
        const int eb = (gy * W + gx) * CO + quad * 4;
        #pragma unroll
        for (int nt = 0; nt < 4; ++nt) {
            const int idx = eb + nt * 16;
            f32x4 np = acc[nt] + oldv[t][nt];
            f32x4 spk, pot;
            #pragma unroll
            for (int j = 0; j < 4; ++j) {
                const bool s = np[j] >= 1.0f;
                spk[j] = s ? 1.0f : 0.0f;
                pot[j] = s ? 0.0f : np[j];
            }
            *(f32x4*)(out_spk + idx) = spk;
            *(f32x4*)(out_pot + idx) = pot;
        }

        if (t + PF < NTILES) issue(t + PF);   // buffer t+PF free: distance-3
    }
}

extern "C" void kernel_launch(void* const* d_in, const int* in_sizes, int n_in,
                              void* d_out, int out_size, void* d_ws, size_t ws_size,
                              hipStream_t stream) {
    const float* in   = (const float*)d_in[0];     // (1,512,512,16)
    const float* w    = (const float*)d_in[1];     // (3,3,16,64)
    const float* oldp = (const float*)d_in[2];     // (1,512,512,64)
    float* out_spk = (float*)d_out;
    float* out_pot = out_spk + (size_t)H * W * CO;
    unsigned short* ws = (unsigned short*)d_ws;

    const int setup_grid = (PAD_PX + 255) / 256 + 1;   // +1 block for weights
    snn_setup<<<setup_grid, 256, 0, stream>>>(in, w, ws);

    const int grid = 32 * 16;                          // 512 blocks x 256 thr
    snn_conv_mfma<<<grid, 256, 0, stream>>>(ws, oldp, out_spk, out_pot);
}

// Round 6
// 214.143 us; speedup vs baseline: 1.0830x; 1.0830x over previous
//
#include <hip/hip_runtime.h>

// SNN conv layer: 3x3x16->64 conv (SAME) on 512x512 NHWC + old_potentials,
// threshold 1.0 -> (spikes, reset potentials).
// R5:  bf16 implicit-GEMM mfma_f32_16x16x32_bf16 (93.5us kernel).
// R6:  A=weights/co, B=pixels swap -> dwordx4 epilogue (~78us).
// R7-R10: entry-prefetch / barrier-pipeline / LDS-free stream / register
//   distance-3 pipeline: ALL NEUTRAL (~80us). R10's pipeline likely collapsed
//   under VGPR pressure (~240 live vs 256 cap -> scheduler sinks prefetch).
// R11: third structural family -- FIRE-AND-FORGET staging via global_load_lds
//   (width 16). Stores are fire-and-forget (why fillBuffer hits 6.7 TB/s at
//   9% occupancy); global_load_lds makes the LOADS fire-and-forget too: no
//   VGPR destination, no per-value wait. Per block: ~31 DMA instrs (oldp
//   32KB + prepacked bf16 input halo 12KB), ONE __syncthreads drain, compute
//   from LDS, stream stores. Latency paid once per block, not per chain.
//   Accepted: 16-way bank conflict on oldp LDS read-back (~2us/CU), 4-way on
//   input reads. VGPR ~150, LDS 44KB -> 3 blocks/CU, 12 waves/CU.
//   Falsification: if this too lands ~80us, all three structural families
//   are exhausted -> floor is environmental -> declare roofline.

#define H 512
#define W 512
#define CI 16
#define CO 64
#define PW 514               // padded width/height
#define PAD_PX (PW * PW)
#define W3_OFF_U16 0         // weight fragments: 1280 x 16B = 20KB
#define IN_OFF_U16 32768     // padded input at d_ws byte 65536
#define TXP 32               // px per block in x
#define TYP 4                // rows per block (1 per wave)

typedef float v4f __attribute__((ext_vector_type(4)));
typedef float f32x4 __attribute__((ext_vector_type(4)));
typedef short short8 __attribute__((ext_vector_type(8)));
typedef unsigned int uint4v __attribute__((ext_vector_type(4)));

__device__ __forceinline__ unsigned int pack2bf(float f0, float f1) {
    // round-to-nearest-even bf16 truncation of two floats, packed
    unsigned u0 = __builtin_bit_cast(unsigned, f0);
    unsigned u1 = __builtin_bit_cast(unsigned, f1);
    u0 = (u0 + 0x7FFFu + ((u0 >> 16) & 1u)) >> 16;
    u1 = (u1 + 0x7FFFu + ((u1 >> 16) & 1u)) >> 16;
    return u0 | (u1 << 16);
}

// fire-and-forget 1KB wave DMA: LDS dest = wave-uniform base + lane*16,
// global src = per-lane (src + lane*16). No VGPR destination, no wait here.
__device__ __forceinline__ void gload_lds16(void* lds, const void* g) {
    __builtin_amdgcn_global_load_lds(
        (const __attribute__((address_space(1))) unsigned int*)g,
        (__attribute__((address_space(3))) unsigned int*)lds, 16, 0, 0);
}

// ---- setup: blocks 0..N-2: pad+convert input f32 -> bf16 [514][514][16]
//            last block: build weight FRAGMENTS bf16 [ks5][nt][lane][8]
__global__ void snn_setup(const float* __restrict__ in,
                          const float* __restrict__ w,
                          unsigned short* __restrict__ ws)
{
    const int tid = threadIdx.x;
    if (blockIdx.x == gridDim.x - 1) {
        // fragment f = (ks5*4 + nt)*64 + lane; element j = w[k0+j][co] where
        // co = nt*16 + (lane&15), k0 = ks5<4 ? ks5*32+(lane>>4)*8
        //                                    : 128+((lane>>4)&1)*8.
        uint4v* wf = (uint4v*)(ws + W3_OFF_U16);
        #pragma unroll
        for (int i = 0; i < 5; ++i) {
            const int f    = i * 256 + tid;        // 0..1279
            const int ks5  = f >> 8;
            const int rem  = f & 255;
            const int nt   = rem >> 6;
            const int lane = rem & 63;
            const int rr   = lane & 15;
            const int quad = lane >> 4;
            const int k0   = (ks5 < 4) ? (ks5 * 32 + quad * 8)
                                       : (128 + (quad & 1) * 8);
            const int co   = nt * 16 + rr;
            uint4v v;
            #pragma unroll
            for (int m = 0; m < 4; ++m)
                v[m] = pack2bf(w[(k0 + 2 * m) * CO + co],
                               w[(k0 + 2 * m + 1) * CO + co]);
            wf[f] = v;
        }
        return;
    }
    // ---- padded input pixel (1-px zero border)
    const int p = blockIdx.x * 256 + tid;
    if (p >= PAD_PX) return;
    const int py = p / PW, px = p - py * PW;
    uint4v pk0 = (uint4v)0u, pk1 = (uint4v)0u;
    if (py >= 1 && py <= H && px >= 1 && px <= W) {
        const v4f* q = (const v4f*)(in + ((py - 1) * W + (px - 1)) * CI);
        v4f a = q[0], b = q[1], c = q[2], d = q[3];
        pk0 = (uint4v){pack2bf(a.x, a.y), pack2bf(a.z, a.w),
                       pack2bf(b.x, b.y), pack2bf(b.z, b.w)};
        pk1 = (uint4v){pack2bf(c.x, c.y), pack2bf(c.z, c.w),
                       pack2bf(d.x, d.y), pack2bf(d.z, d.w)};
    }
    uint4v* dst = (uint4v*)(ws + IN_OFF_U16 + p * CI);
    dst[0] = pk0;
    dst[1] = pk1;
}

__global__ __launch_bounds__(256, 3)
void snn_conv_mfma(const unsigned short* __restrict__ ws,
                   const float* __restrict__ oldp,
                   float* __restrict__ out_spk,
                   float* __restrict__ out_pot)
{
    // s_old: [4 rows][32 px][64 co] f32, linear as DMA'd  (32768 B)
    // s_i:   [6 rows][64 px][16 ci] bf16, linear as DMA'd (12288 B)
    __shared__ float s_old[TYP * TXP * CO];
    __shared__ unsigned short s_i[6 * 64 * CI];

    const unsigned short* pin = ws + IN_OFF_U16;   // [PW][PW][16] bf16, padded

    const int tid  = threadIdx.x;
    const int bx   = blockIdx.x & 15;    // 16 x-tiles (32 px each)
    const int by   = blockIdx.x >> 4;    // 128 y-tiles (4 rows each)
    const int lane = tid & 63;
    const int wv   = tid >> 6;           // wave 0..3 -> one output row
    const int r    = lane & 15;          // pixel-within-16 (B/D) / co-within-16 (A)
    const int quad = lane >> 4;          // 0..3
    const int half = quad & 1;           // ci-half for pixel fragment
    const int tsel = quad >> 1;          // tap parity within K-step

    const int gy0 = by * TYP;
    const int gx0 = bx * TXP;

    // ---- fire-and-forget staging: oldp row (8 chunks x 1KB per wave)
    {
        const char* src = (const char*)(oldp + ((gy0 + wv) * W + gx0) * CO)
                          + lane * 16;
        char* dst = (char*)s_old + wv * 8192;
        #pragma unroll
        for (int c = 0; c < 8; ++c)
            gload_lds16(dst + c * 1024, src + c * 1024);
    }
    // ---- input halo: 6 padded rows x 64 px x 32B = 12 chunks; wave wv does 3.
    // Staged x-range: xs = gx0-16 .. gx0+47 (consumed: local px 16..49).
    // Out-of-range source bytes land in unused LDS slots (never read, no fault:
    // d_ws is 512MiB and offsets stay within it).
    {
        const int xs = gx0 - 16;
        #pragma unroll
        for (int k = 0; k < 3; ++k) {
            const int c   = wv * 3 + k;          // 0..11
            const int row = c >> 1, hf = c & 1;
            const char* src = (const char*)(pin + ((gy0 + row) * PW + xs) * CI)
                              + hf * 1024 + lane * 16;
            char* dst = (char*)s_i + row * 2048 + hf * 1024;
            gload_lds16(dst, src);
        }
    }

    // ---- weight fragments -> registers (L2-hot 20KB, every block reads same)
    short8 bf[5][4];
    #pragma unroll
    for (int ks5 = 0; ks5 < 5; ++ks5)
        #pragma unroll
        for (int nt = 0; nt < 4; ++nt)
            bf[ks5][nt] = *(const short8*)&ws[(ks5 * 256 + nt * 64 + lane) * 8];

    __syncthreads();   // the ONE drain point: vmcnt(0)+lgkmcnt(0)+barrier

    // ---- implicit GEMM from LDS: A = weight frag (M=co), B = pixel frag
    f32x4 acc[2][4] = {};
    const short8 zero8 = {0, 0, 0, 0, 0, 0, 0, 0};
    #pragma unroll
    for (int ks5 = 0; ks5 < 5; ++ks5) {
        const int t8 = (ks5 == 4) ? 8 : (2 * ks5 + tsel);
        const int dy = t8 / 3, dx = t8 % 3;
        short8 af[2];
        #pragma unroll
        for (int mt = 0; mt < 2; ++mt) {
            // local px = (output x within tile) + dx + 16  (halo offset)
            const int px = mt * 16 + r + dx + 16;
            short8 a = *(const short8*)&s_i[((wv + dy) * 64 + px) * CI + half * 8];
            if (ks5 == 4) a = (quad >= 2) ? zero8 : a;   // zero pad k=144..159
            af[mt] = a;
        }
        #pragma unroll
        for (int mt = 0; mt < 2; ++mt)
            #pragma unroll
            for (int nt = 0; nt < 4; ++nt)
                acc[mt][nt] = __builtin_amdgcn_mfma_f32_16x16x32_bf16(
                    bf[ks5][nt], af[mt], acc[mt][nt], 0, 0, 0);
    }

    // ---- epilogue: D col=lane&15 (pixel), row=quad*4+reg (co-within-16);
    // oldv from LDS (16-way conflicted read, accepted), fused threshold,
    // dwordx4 streaming stores.
    #pragma unroll
    for (int mt = 0; mt < 2; ++mt) {
        const int gxo = gx0 + mt * 16 + r;
        const int eb  = ((gy0 + wv) * W + gxo) * CO + quad * 4;
        #pragma unroll
        for (int nt = 0; nt < 4; ++nt) {
            const f32x4 ov = *(const f32x4*)
                &s_old[(wv * TXP + mt * 16 + r) * CO + nt * 16 + quad * 4];
            const int idx = eb + nt * 16;
            f32x4 np = acc[mt][nt] + ov;
            f32x4 spk, pot;
            #pragma unroll
            for (int j = 0; j < 4; ++j) {
                const bool s = np[j] >= 1.0f;
                spk[j] = s ? 1.0f : 0.0f;
                pot[j] = s ? 0.0f : np[j];
            }
            *(f32x4*)(out_spk + idx) = spk;
            *(f32x4*)(out_pot + idx) = pot;
        }
    }
}

extern "C" void kernel_launch(void* const* d_in, const int* in_sizes, int n_in,
                              void* d_out, int out_size, void* d_ws, size_t ws_size,
                              hipStream_t stream) {
    const float* in   = (const float*)d_in[0];     // (1,512,512,16)
    const float* w    = (const float*)d_in[1];     // (3,3,16,64)
    const float* oldp = (const float*)d_in[2];     // (1,512,512,64)
    float* out_spk = (float*)d_out;
    float* out_pot = out_spk + (size_t)H * W * CO;
    unsigned short* ws = (unsigned short*)d_ws;

    const int setup_grid = (PAD_PX + 255) / 256 + 1;   // +1 block for weights
    snn_setup<<<setup_grid, 256, 0, stream>>>(in, w, ws);

    const int grid = (W / TXP) * (H / TYP);            // 2048 blocks x 256 thr
    snn_conv_mfma<<<grid, 256, 0, stream>>>(ws, oldp, out_spk, out_pot);
}